// Round 9
// baseline (151.664 us; speedup 1.0000x reference)
//
#include <hip/hip_runtime.h>

#define MM 4096
#define NN 4096
#define KK 4096
#define BM 256
#define BN 128
#define BK 32
#define NT (KK / BK)

typedef short          s16x8 __attribute__((ext_vector_type(8)));
typedef float          f32x4 __attribute__((ext_vector_type(4)));
typedef unsigned short us4   __attribute__((ext_vector_type(4)));
typedef unsigned short us8   __attribute__((ext_vector_type(8)));

#define MFMA16(a, b, c) __builtin_amdgcn_mfma_f32_16x16x32_bf16((a), (b), (c), 0, 0, 0)
#define SB0() __builtin_amdgcn_sched_barrier(0)
#define LGKM(n) asm volatile("s_waitcnt lgkmcnt(" #n ")" ::: "memory")
#define VMC(n)  asm volatile("s_waitcnt vmcnt(" #n ")" ::: "memory")

// ---------- helpers ----------

__device__ __forceinline__ unsigned short f2bf(float f) {
  unsigned int u = __float_as_uint(f);
  u += 0x7fffu + ((u >> 16) & 1u);
  return (unsigned short)(u >> 16);
}

__device__ __forceinline__ void gload16(const void* g, void* l) {
  __builtin_amdgcn_global_load_lds(
      (const __attribute__((address_space(1))) void*)g,
      (__attribute__((address_space(3))) void*)l, 16, 0, 0);
}

// ---------- kernel 1: 2:4 mask + binarize + cvt -> bf16 W_h (M x K) ----------

__global__ __launch_bounds__(256) void kquant(const float* __restrict__ w,
                                              unsigned short* __restrict__ wh) {
  int idx = blockIdx.x * 256 + threadIdx.x;
  const float4* p = (const float4*)w;
  float4 g0 = p[(size_t)idx * 2];
  float4 g1 = p[(size_t)idx * 2 + 1];
  float v[8] = {g0.x, g0.y, g0.z, g0.w, g1.x, g1.y, g1.z, g1.w};
  us8 o;
#pragma unroll
  for (int g = 0; g < 2; g++) {
    float av[4];
#pragma unroll
    for (int j = 0; j < 4; j++) av[j] = fabsf(v[g * 4 + j]);
#pragma unroll
    for (int j = 0; j < 4; j++) {
      int rank = 0;
#pragma unroll
      for (int k = 0; k < 4; k++) {
        if (k == j) continue;
        rank += (av[k] > av[j] || (av[k] == av[j] && k < j)) ? 1 : 0;
      }
      o[g * 4 + j] = (rank < 2 && v[g * 4 + j] > 0.0f) ? (unsigned short)0x3F80
                                                       : (unsigned short)0;
    }
  }
  *(us8*)(wh + (size_t)idx * 8) = o;
}

// ---------- kernel 2: x (K x N f32) -> xT (N x K bf16) ----------

__global__ __launch_bounds__(256) void ktranspose(const float* __restrict__ x,
                                                  unsigned short* __restrict__ xt) {
  __shared__ float tile[64][65];
  int bn = blockIdx.x;
  int bk = blockIdx.y;
  int t = threadIdx.x;
  int tc = (t & 15) << 2;
  int tr = t >> 4;
  const float* src = x + (size_t)(bk * 64 + tr) * NN + bn * 64 + tc;
#pragma unroll
  for (int i = 0; i < 4; i++) {
    float4 v = *(const float4*)(src + (size_t)i * 16 * NN);
    int r = tr + i * 16;
    tile[r][tc + 0] = v.x; tile[r][tc + 1] = v.y;
    tile[r][tc + 2] = v.z; tile[r][tc + 3] = v.w;
  }
  __syncthreads();
  unsigned short* dst = xt + (size_t)(bn * 64 + tr) * KK + bk * 64 + tc;
#pragma unroll
  for (int i = 0; i < 4; i++) {
    int n = tr + i * 16;
    us4 o;
    o.x = f2bf(tile[tc + 0][n]);
    o.y = f2bf(tile[tc + 1][n]);
    o.z = f2bf(tile[tc + 2][n]);
    o.w = f2bf(tile[tc + 3][n]);
    *(us4*)(dst + (size_t)i * 16 * KK) = o;
  }
}

// ---------- kernel 3: 256x128 GEMM, BK=32 dbuf, 2 blocks/CU (TLP) ----------
// 4 waves (2M x 2N), wave-tile 128x64 (same per-output LDS traffic as the
// 256^2/8-wave version). LDS 48 KiB -> 2 independent blocks per CU: barrier
// stalls of one block are covered by the other, so the LDS and MFMA pipes
// overlap via TLP instead of intra-wave scheduling. 64B rows swizzled with
// granule ^= (row>>1)&3 (2 lanes/bank per 16-lane phase = free).

__global__ __launch_bounds__(256, 2) void kgemm(const unsigned short* __restrict__ A,
                                                const unsigned short* __restrict__ B,
                                                float* __restrict__ C) {
  __shared__ __align__(16) unsigned short lds[24576];  // A[2][256][32] | B[2][128][32]

  const int tid  = threadIdx.x;
  // XCD swizzle: bijective over the 16(M) x 32(N) block grid.
  const int bid  = blockIdx.x;
  const int xcd  = bid & 7;
  const int j    = bid >> 3;                 // 0..63
  const int bmi  = (xcd & 1) * 8 + (j >> 3); // 0..15
  const int bni  = (xcd >> 1) * 8 + (j & 7); // 0..31
  const int lane = tid & 63;
  const int wave = tid >> 6;
  const int wm   = wave >> 1;   // 0..1
  const int wn   = wave & 1;    // 0..1
  const int llo  = lane & 15;
  const int lhi  = lane >> 4;   // 0..3

  // staging (linear LDS dest; inverse-swizzled global source)
  const int srow  = tid >> 2;                               // 0..63 per chunk
  const int sgran = (tid & 3) ^ ((tid >> 3) & 3);           // g ^ ((row>>1)&3)
  const unsigned short* gaA0 = A + (size_t)(bmi * BM + srow) * KK + sgran * 8;
  const unsigned short* gbB0 = B + (size_t)(bni * BN + srow) * KK + sgran * 8;

  // fragment read offsets (swizzled): col = lhi*8 ^ ((llo>>1)&3)*8 elems
  const int okf  = ((lhi << 3) ^ (((llo >> 1) & 3) << 3));
  const int arow = (wm * 128 + llo) * BK;
  const int brow = (wn * 64 + llo) * BK;

  f32x4 acc[8][4] = {};
  s16x8 af[8], bf[4];

  auto stage = [&](int buf, int t) {   // 4 A-gloads + 2 B-gloads
    const unsigned short* pa = gaA0 + (size_t)t * BK;
    const unsigned short* pb = gbB0 + (size_t)t * BK;
    unsigned short* la = &lds[buf * 8192 + tid * 8];
    unsigned short* lb = &lds[16384 + buf * 4096 + tid * 8];
#pragma unroll
    for (int h = 0; h < 4; h++)
      gload16(pa + (size_t)h * 64 * KK, la + h * 2048);
#pragma unroll
    for (int h = 0; h < 2; h++)
      gload16(pb + (size_t)h * 64 * KK, lb + h * 2048);
  };

  // prologue: tile 0 -> buf0
  stage(0, 0);
  VMC(0); SB0();
  __builtin_amdgcn_s_barrier(); SB0();

  for (int t = 0; t < NT; ++t) {
    const int cur = t & 1;
    const unsigned short* sa = &lds[cur * 8192];
    const unsigned short* sb = &lds[16384 + cur * 4096];
    const int tn = (t + 1) & (NT - 1);   // wraps on last iter (dead loads)

    // stage tile t+1 into buf^1 (readers of buf^1 retired before last barrier)
    stage(cur ^ 1, tn);
    SB0();

    // issue reads: [af0-3, bf0-3] then [af4-7]
#pragma unroll
    for (int m = 0; m < 4; m++)
      af[m] = *(const s16x8*)(sa + arow + m * 512 + okf);
#pragma unroll
    for (int n = 0; n < 4; n++)
      bf[n] = *(const s16x8*)(sb + brow + n * 512 + okf);
    SB0();
#pragma unroll
    for (int m = 4; m < 8; m++)
      af[m] = *(const s16x8*)(sa + arow + m * 512 + okf);
    SB0();

    // first half: af0-3 x bf0-3 ready after LGKM(4)
    LGKM(4); SB0();
    __builtin_amdgcn_s_setprio(1);
#pragma unroll
    for (int m = 0; m < 4; m++)
#pragma unroll
      for (int n = 0; n < 4; n++)
        acc[m][n] = MFMA16(af[m], bf[n], acc[m][n]);
    __builtin_amdgcn_s_setprio(0);
    SB0();

    // second half: af4-7
    LGKM(0); SB0();
    __builtin_amdgcn_s_setprio(1);
#pragma unroll
    for (int m = 4; m < 8; m++)
#pragma unroll
      for (int n = 0; n < 4; n++)
        acc[m][n] = MFMA16(af[m], bf[n], acc[m][n]);
    __builtin_amdgcn_s_setprio(0);
    SB0();

    // certify buf^1 (6 gloads issued at tile top; ~full tile of cover)
    VMC(0); SB0();
    __builtin_amdgcn_s_barrier(); SB0();
  }

  // ---- epilogue: D layout col = lane&15, row = (lane>>4)*4 + reg ----
  const int crow0 = bmi * BM + wm * 128 + lhi * 4;
  const int ccol0 = bni * BN + wn * 64 + llo;
#pragma unroll
  for (int m = 0; m < 8; m++)
#pragma unroll
    for (int n = 0; n < 4; n++) {
      float* cp = C + (size_t)(crow0 + m * 16) * NN + ccol0 + n * 16;
#pragma unroll
      for (int v = 0; v < 4; v++) cp[(size_t)v * NN] = acc[m][n][v];
    }
}

// ---------- fallback: fused fp32 tiled GEMM (workspace too small) ----------

__device__ __forceinline__ float binq_elem(const float g[4], int j) {
  float aj = fabsf(g[j]);
  int rank = 0;
#pragma unroll
  for (int k = 0; k < 4; k++) {
    if (k == j) continue;
    float ak = fabsf(g[k]);
    rank += (ak > aj || (ak == aj && k < j)) ? 1 : 0;
  }
  return (rank < 2 && g[j] > 0.0f) ? 1.0f : 0.0f;
}

__global__ __launch_bounds__(256) void kfallback(const float* __restrict__ x,
                                                 const float* __restrict__ w,
                                                 float* __restrict__ c) {
  __shared__ float sA[16][17];
  __shared__ float sB[16][17];
  int tx = threadIdx.x, ty = threadIdx.y;
  int row = blockIdx.y * 16 + ty;
  int col = blockIdx.x * 16 + tx;
  float acc = 0.0f;
  for (int k0 = 0; k0 < KK; k0 += 16) {
    int k = k0 + tx;
    const float* g = &w[(size_t)row * KK + (k & ~3)];
    float gv[4] = {g[0], g[1], g[2], g[3]};
    sA[ty][tx] = binq_elem(gv, k & 3);
    sB[ty][tx] = x[(size_t)(k0 + ty) * NN + col];
    __syncthreads();
#pragma unroll
    for (int kk = 0; kk < 16; kk++) acc += sA[ty][kk] * sB[kk][tx];
    __syncthreads();
  }
  c[(size_t)row * NN + col] = acc;
}

// ---------- launcher ----------

extern "C" void kernel_launch(void* const* d_in, const int* in_sizes, int n_in,
                              void* d_out, int out_size, void* d_ws, size_t ws_size,
                              hipStream_t stream) {
  const float* x = (const float*)d_in[0];
  const float* w = (const float*)d_in[1];
  float* out = (float*)d_out;

  const size_t need = (size_t)MM * KK * 2 + (size_t)NN * KK * 2;
  if (ws_size < need) {
    dim3 blk(16, 16);
    dim3 grd(NN / 16, MM / 16);
    kfallback<<<grd, blk, 0, stream>>>(x, w, out);
    return;
  }

  unsigned short* wh = (unsigned short*)d_ws;
  unsigned short* xt = wh + (size_t)MM * KK;

  kquant<<<(MM * (size_t)KK / 8) / 256, 256, 0, stream>>>(w, wh);
  ktranspose<<<dim3(NN / 64, KK / 64), 256, 0, stream>>>(x, xt);
  kgemm<<<dim3((MM / BM) * (NN / BN)), 256, 0, stream>>>(wh, xt, out);
}